// Round 1
// baseline (58.533 us; speedup 1.0000x reference)
//
#include <hip/hip_runtime.h>
#include <hip/hip_bf16.h>

// GAT fused kernel for MI355X (gfx950).
// B=32, N=1024, F_IN=F_OUT=64, ALPHA=0.2
//
// Key structure:
//  e[b,i,j] = leakyrelu(f1[i]+f2[j]) is rank-1: no QK GEMM.
//  f1+f2 bounded (~|9|) -> exp without max-subtraction is safe in f32:
//  single pass over j accumulating numerator (MFMA, bf16) and denominator (VALU, f32).
//
// Kernel 1 (prep): h = nf@W (f32), f1 = h.a1, f2 = h.a2, and h stored as bf16 in
//   MFMA-16x16x32 B-fragment order (lane-contiguous 16B) for kernel 2.
// Kernel 2 (attn): one wave = 16 output rows. Loop 32 j-chunks of 32:
//   build P A-frag from adjacency(int32) + expf, 4x mfma_f32_16x16x32_bf16,
//   accumulate row-sums of p; epilogue: divide, ELU, store.

#define B_  32
#define N_  1024
#define F_  64

typedef __attribute__((ext_vector_type(8))) short  short8;
typedef __attribute__((ext_vector_type(4))) float  floatx4;

__device__ __forceinline__ short f2bf(float x) {
    unsigned u = __float_as_uint(x);
    u += 0x7fff + ((u >> 16) & 1);   // RNE
    return (short)(u >> 16);
}

// ---------------- Kernel 1: prep ----------------
// grid = B*N/16 blocks, 256 threads = 4 waves, each wave computes 4 rows.
// lane = output feature f (0..63).
__global__ __launch_bounds__(256) void gat_prep(
    const float* __restrict__ nf, const float* __restrict__ W, const float* __restrict__ a,
    float* __restrict__ f1, float* __restrict__ f2, short* __restrict__ h_swz)
{
    const int wave = threadIdx.x >> 6;
    const int lane = threadIdx.x & 63;
    const long long row0 = (long long)blockIdx.x * 16 + wave * 4;

    const float* nf0 = nf + row0 * F_;
    float acc0 = 0.f, acc1 = 0.f, acc2 = 0.f, acc3 = 0.f;
    #pragma unroll 8
    for (int k = 0; k < F_; ++k) {
        float wk = W[k * F_ + lane];
        acc0 = fmaf(nf0[k],          wk, acc0);
        acc1 = fmaf(nf0[F_ + k],     wk, acc1);
        acc2 = fmaf(nf0[2 * F_ + k], wk, acc2);
        acc3 = fmaf(nf0[3 * F_ + k], wk, acc3);
    }
    const float a1 = a[lane], a2 = a[F_ + lane];

    float accs[4] = {acc0, acc1, acc2, acc3};
    #pragma unroll
    for (int r = 0; r < 4; ++r) {
        float v  = accs[r];
        float s1 = v * a1, s2 = v * a2;
        #pragma unroll
        for (int off = 32; off >= 1; off >>= 1) {
            s1 += __shfl_xor(s1, off, 64);
            s2 += __shfl_xor(s2, off, 64);
        }
        long long row = row0 + r;
        if (lane == 0) { f1[row] = s1; f2[row] = s2; }
        // swizzled bf16 store: B-frag layout for mfma_f32_16x16x32_bf16.
        // value h[j][f] -> chunk gc=row/32, k=row%32, fg=f>>4, n=f&15,
        // lane' = n | ((k>>3)<<4), e = k&7
        int jl = (int)(row & (N_ - 1));
        int k  = jl & 31;
        int n  = lane & 15, fg = lane >> 4;
        int lp = n | ((k >> 3) << 4), e = k & 7;
        long long gc = row >> 5;   // global 32-row chunk id
        h_swz[(gc * 4 + fg) * 512 + lp * 8 + e] = f2bf(v);
    }
}

// ---------------- Kernel 2: fused attention ----------------
// grid = B * (N/64) blocks, 256 threads = 4 waves; wave owns 16 i-rows.
__global__ __launch_bounds__(256) void gat_attn(
    const int* __restrict__ adj, const float* __restrict__ f1g, const float* __restrict__ f2g,
    const short* __restrict__ h_swz, float* __restrict__ out)
{
    const int wave = threadIdx.x >> 6;
    const int lane = threadIdx.x & 63;
    const int b  = blockIdx.x >> 4;        // N/64 = 16 i-blocks per batch
    const int ib = blockIdx.x & 15;
    const int i_base = ib * 64 + wave * 16;
    const int iw = lane & 15;              // A-frag row within 16
    const int kg = lane >> 4;              // A-frag k-group (8 k's each)
    const int i  = i_base + iw;

    const float f1i = f1g[b * N_ + i];
    const int*   adjrow = adj + ((long long)b * N_ + i) * N_ + kg * 8;
    const float* f2b    = f2g + b * N_ + kg * 8;
    const short* hb     = h_swz + (long long)b * 65536 + lane * 8;

    floatx4 acc0 = {0.f,0.f,0.f,0.f}, acc1 = {0.f,0.f,0.f,0.f};
    floatx4 acc2 = {0.f,0.f,0.f,0.f}, acc3 = {0.f,0.f,0.f,0.f};
    float s_lane = 0.f;

    for (int jc = 0; jc < 32; ++jc) {
        int4 aA = *(const int4*)(adjrow + jc * 32);
        int4 aB = *(const int4*)(adjrow + jc * 32 + 4);
        floatx4 fA = *(const floatx4*)(f2b + jc * 32);
        floatx4 fB = *(const floatx4*)(f2b + jc * 32 + 4);

        int   am[8] = {aA.x, aA.y, aA.z, aA.w, aB.x, aB.y, aB.z, aB.w};
        float fv[8] = {fA[0], fA[1], fA[2], fA[3], fB[0], fB[1], fB[2], fB[3]};

        short8 afrag;
        #pragma unroll
        for (int e = 0; e < 8; ++e) {
            float x  = f1i + fv[e];
            x        = fmaxf(x, 0.2f * x);          // leaky relu
            float pe = am[e] ? __expf(x) : 0.f;     // masked exp (no max-sub needed)
            s_lane  += pe;
            afrag[e] = f2bf(pe);
        }

        const short* hc = hb + jc * 2048;
        short8 b0 = *(const short8*)(hc);
        short8 b1 = *(const short8*)(hc + 512);
        short8 b2 = *(const short8*)(hc + 1024);
        short8 b3 = *(const short8*)(hc + 1536);

        acc0 = __builtin_amdgcn_mfma_f32_16x16x32_bf16(afrag, b0, acc0, 0, 0, 0);
        acc1 = __builtin_amdgcn_mfma_f32_16x16x32_bf16(afrag, b1, acc1, 0, 0, 0);
        acc2 = __builtin_amdgcn_mfma_f32_16x16x32_bf16(afrag, b2, acc2, 0, 0, 0);
        acc3 = __builtin_amdgcn_mfma_f32_16x16x32_bf16(afrag, b3, acc3, 0, 0, 0);
    }

    // full denominator per row: sum over the 4 k-group lanes holding row iw
    s_lane += __shfl_xor(s_lane, 16, 64);
    s_lane += __shfl_xor(s_lane, 32, 64);

    // epilogue: divide, ELU, store.  C layout: col=lane&15, row=(lane>>4)*4+reg
    float* orow = out + ((long long)b * N_ + i_base) * F_;
    floatx4 accs[4] = {acc0, acc1, acc2, acc3};
    #pragma unroll
    for (int fg = 0; fg < 4; ++fg) {
        #pragma unroll
        for (int r = 0; r < 4; ++r) {
            int rloc = kg * 4 + r;
            float sr = __shfl(s_lane, rloc, 64);
            float v  = accs[fg][r] / sr;
            v = v > 0.f ? v : (__expf(v) - 1.f);    // ELU (alpha=1)
            orow[(long long)rloc * F_ + fg * 16 + iw] = v;
        }
    }
}

extern "C" void kernel_launch(void* const* d_in, const int* in_sizes, int n_in,
                              void* d_out, int out_size, void* d_ws, size_t ws_size,
                              hipStream_t stream) {
    const float* nf  = (const float*)d_in[0];
    const int*   adj = (const int*)d_in[1];     // bool -> int32 per harness
    const float* W   = (const float*)d_in[2];
    const float* a   = (const float*)d_in[3];
    float* out = (float*)d_out;

    char* ws = (char*)d_ws;
    float* f1    = (float*)ws;                    // B*N f32 = 128KB
    float* f2    = (float*)(ws + 131072);         // B*N f32 = 128KB
    short* h_swz = (short*)(ws + 262144);         // B*N*64 bf16 = 4MB

    hipLaunchKernelGGL(gat_prep, dim3(B_ * N_ / 16), dim3(256), 0, stream,
                       nf, W, a, f1, f2, h_swz);
    hipLaunchKernelGGL(gat_attn, dim3(B_ * (N_ / 64)), dim3(256), 0, stream,
                       adj, f1, f2, h_swz, out);
}